// Round 9
// baseline (970.175 us; speedup 1.0000x reference)
//
#include <hip/hip_runtime.h>

#define N_NODES 10000
#define N_EDGES 320000
#define IN_F    512
#define H1F     256
#define H2F     64

// ---------- edge-order classify: sel=0 dict (ew,src,dst), sel=1 alpha (dst,src,ew) ----------
// fp32 weights read as int32 are ~never in [0,N_NODES); int indices always are.
__global__ __launch_bounds__(1024) void k_classify(const int* __restrict__ c0,
                                                   const int* __restrict__ c2,
                                                   int* __restrict__ sel) {
    __shared__ int cnt0, cnt2;
    if (threadIdx.x == 0) { cnt0 = 0; cnt2 = 0; }
    __syncthreads();
    int v0 = c0[threadIdx.x];
    int v2 = c2[threadIdx.x];
    if (v0 >= 0 && v0 < N_NODES) atomicAdd(&cnt0, 1);
    if (v2 >= 0 && v2 < N_NODES) atomicAdd(&cnt2, 1);
    __syncthreads();
    if (threadIdx.x == 0) *sel = (cnt0 > 900 && cnt2 <= 900) ? 1 : 0;
}

// ---------- GEMM1: sup1[10000,256] = x[10000,512] @ W1[512,256], 8 nodes/block ----------
__global__ __launch_bounds__(256) void k_gemm1(const float* __restrict__ x,
                                               const float* __restrict__ W1,
                                               float* __restrict__ sup1) {
    __shared__ float xs[IN_F][8];   // 16 KB, [k][node]
    int nb = blockIdx.x * 8;
    int t = threadIdx.x;
    {
        int n  = t & 7;
        int k0 = (t >> 3) * 16;
        const float* xr = x + (size_t)(nb + n) * IN_F + k0;
        #pragma unroll
        for (int c = 0; c < 16; c += 4) {
            float4 v = *(const float4*)(xr + c);
            xs[k0 + c + 0][n] = v.x;
            xs[k0 + c + 1][n] = v.y;
            xs[k0 + c + 2][n] = v.z;
            xs[k0 + c + 3][n] = v.w;
        }
    }
    __syncthreads();
    int f = t;
    float acc[8] = {0.f,0.f,0.f,0.f,0.f,0.f,0.f,0.f};
    #pragma unroll 8
    for (int k = 0; k < IN_F; ++k) {
        float w = W1[(size_t)k * H1F + f];      // coalesced across lanes
        float4 a = *(const float4*)&xs[k][0];   // broadcast
        float4 b = *(const float4*)&xs[k][4];
        acc[0] += a.x * w; acc[1] += a.y * w; acc[2] += a.z * w; acc[3] += a.w * w;
        acc[4] += b.x * w; acc[5] += b.y * w; acc[6] += b.z * w; acc[7] += b.w * w;
    }
    #pragma unroll
    for (int n = 0; n < 8; ++n)
        sup1[(size_t)(nb + n) * H1F + f] = acc[n];
}

// ---------- GEMM2: sup2[10000,64] = h1[10000,256] @ W2[256,64], 4 nodes/block ----------
__global__ __launch_bounds__(64) void k_gemm2(const float* __restrict__ h1,
                                              const float* __restrict__ W2,
                                              float* __restrict__ sup2) {
    __shared__ float hs[H1F][4];   // 4 KB
    int nb = blockIdx.x * 4;
    int t = threadIdx.x;
    {
        int n  = t & 3;
        int k0 = (t >> 2) * 16;
        const float* hr = h1 + (size_t)(nb + n) * H1F + k0;
        #pragma unroll
        for (int c = 0; c < 16; c += 4) {
            float4 v = *(const float4*)(hr + c);
            hs[k0 + c + 0][n] = v.x;
            hs[k0 + c + 1][n] = v.y;
            hs[k0 + c + 2][n] = v.z;
            hs[k0 + c + 3][n] = v.w;
        }
    }
    __syncthreads();
    int f = t;
    float acc[4] = {0.f,0.f,0.f,0.f};
    #pragma unroll 8
    for (int k = 0; k < H1F; ++k) {
        float w = W2[(size_t)k * H2F + f];
        float4 a = *(const float4*)&hs[k][0];
        acc[0] += a.x * w; acc[1] += a.y * w; acc[2] += a.z * w; acc[3] += a.w * w;
    }
    #pragma unroll
    for (int n = 0; n < 4; ++n)
        sup2[(size_t)(nb + n) * H2F + f] = acc[n];
}

// ---------- forward scatter: agg[dst] += w * sup[src], sel-aware roles ----------
__global__ __launch_bounds__(256) void k_scatter(const float* __restrict__ sup,
                                                 const int* __restrict__ c0,
                                                 const int* __restrict__ c1,
                                                 const int* __restrict__ c2,
                                                 const float* __restrict__ c0f,
                                                 const float* __restrict__ c2f,
                                                 const int* __restrict__ sel,
                                                 float* __restrict__ agg, int F) {
    int e = blockIdx.x;
    int f = threadIdx.x;
    int s = *sel;
    int src = c1[e];                   // src is position 1 in both orderings
    int dst = s ? c0[e] : c2[e];       // dict: dst=c2 ; alpha: dst=c0
    float w = s ? c2f[e] : c0f[e];     // dict: ew=c0  ; alpha: ew=c2
    if ((unsigned)src >= N_NODES || (unsigned)dst >= N_NODES) return;
    atomicAdd(&agg[(size_t)dst * F + f], w * sup[(size_t)src * F + f]);
}

// ---------- bias + relu, in place ----------
__global__ __launch_bounds__(256) void k_bias_relu(float* __restrict__ a,
                                                   const float* __restrict__ bias,
                                                   int n, int fmask) {
    int i = blockIdx.x * 256 + threadIdx.x;
    if (i >= n) return;
    a[i] = fmaxf(a[i] + bias[i & fmask], 0.f);
}

// ---------- decoder: recon = sigmoid(z @ z^T), fp32 in/out, 64x64 tile ----------
__global__ __launch_bounds__(256) void k_decoder(const float* __restrict__ zf,
                                                 float* __restrict__ recon) {
    __shared__ float As[H2F][68];   // [k][i], +4 pad
    __shared__ float Bs[H2F][68];   // [k][j]
    int i0 = blockIdx.y * 64, j0 = blockIdx.x * 64;
    int t = threadIdx.x;
    int li = t & 63;
    int kq = t >> 6;                // 0..3
    #pragma unroll
    for (int rep = 0; rep < 4; ++rep) {
        int k0 = (kq + rep * 4) * 4;
        float4 va = make_float4(0.f, 0.f, 0.f, 0.f);
        float4 vb = make_float4(0.f, 0.f, 0.f, 0.f);
        if (i0 + li < N_NODES) va = *(const float4*)&zf[(size_t)(i0 + li) * H2F + k0];
        if (j0 + li < N_NODES) vb = *(const float4*)&zf[(size_t)(j0 + li) * H2F + k0];
        As[k0 + 0][li] = va.x; As[k0 + 1][li] = va.y; As[k0 + 2][li] = va.z; As[k0 + 3][li] = va.w;
        Bs[k0 + 0][li] = vb.x; Bs[k0 + 1][li] = vb.y; Bs[k0 + 2][li] = vb.z; Bs[k0 + 3][li] = vb.w;
    }
    __syncthreads();

    int tx = t & 15, ty = t >> 4;
    float acc[4][4] = {{0.f}};
    #pragma unroll 4
    for (int k = 0; k < H2F; ++k) {
        float a0 = As[k][ty * 4 + 0], a1 = As[k][ty * 4 + 1];
        float a2 = As[k][ty * 4 + 2], a3 = As[k][ty * 4 + 3];
        float b0 = Bs[k][tx * 4 + 0], b1 = Bs[k][tx * 4 + 1];
        float b2 = Bs[k][tx * 4 + 2], b3 = Bs[k][tx * 4 + 3];
        acc[0][0] += a0 * b0; acc[0][1] += a0 * b1; acc[0][2] += a0 * b2; acc[0][3] += a0 * b3;
        acc[1][0] += a1 * b0; acc[1][1] += a1 * b1; acc[1][2] += a1 * b2; acc[1][3] += a1 * b3;
        acc[2][0] += a2 * b0; acc[2][1] += a2 * b1; acc[2][2] += a2 * b2; acc[2][3] += a2 * b3;
        acc[3][0] += a3 * b0; acc[3][1] += a3 * b1; acc[3][2] += a3 * b2; acc[3][3] += a3 * b3;
    }

    #pragma unroll
    for (int ii = 0; ii < 4; ++ii) {
        int row = i0 + ty * 4 + ii;
        if (row >= N_NODES) continue;
        int col = j0 + tx * 4;
        float o4[4];
        #pragma unroll
        for (int jj = 0; jj < 4; ++jj) {
            float s = acc[ii][jj];
            o4[jj] = 1.0f / (1.0f + __expf(-s));   // s >= 0, no overflow
        }
        size_t base = (size_t)row * N_NODES + col;
        if (col + 4 <= N_NODES) {
            *(float4*)(recon + base) = make_float4(o4[0], o4[1], o4[2], o4[3]);
        } else {
            for (int jj = 0; jj < 4; ++jj)
                if (col + jj < N_NODES) recon[base + jj] = o4[jj];
        }
    }
}

extern "C" void kernel_launch(void* const* d_in, const int* in_sizes, int n_in,
                              void* d_out, int out_size, void* d_ws, size_t ws_size,
                              hipStream_t stream) {
    // Locate inputs by element-count signature; three 320000 arrays keep d_in order,
    // roles resolved on-device by k_classify. Fallback = dict order.
    int ix = -1, iW1 = -1, ib1 = -1, iW2 = -1, ib2 = -1, ic0 = -1, ic1 = -1, ic2 = -1;
    for (int i = 0; i < n_in; ++i) {
        int s = in_sizes[i];
        if      (s == N_NODES * IN_F) ix = i;
        else if (s == IN_F * H1F)     iW1 = i;
        else if (s == H1F)            ib1 = i;
        else if (s == H1F * H2F)      iW2 = i;
        else if (s == H2F)            ib2 = i;
        else if (s == N_EDGES) { if (ic0 < 0) ic0 = i; else if (ic1 < 0) ic1 = i; else ic2 = i; }
    }
    if (ix < 0 || iW1 < 0 || ib1 < 0 || iW2 < 0 || ib2 < 0 || ic0 < 0 || ic1 < 0 || ic2 < 0) {
        ix = 0; iW1 = 1; ib1 = 2; iW2 = 3; ib2 = 4; ic0 = 5; ic1 = 6; ic2 = 7;
    }
    const float* x  = (const float*)d_in[ix];     // ALL float inputs are fp32 (measured R2->R3 + R5)
    const float* W1 = (const float*)d_in[iW1];
    const float* b1 = (const float*)d_in[ib1];
    const float* W2 = (const float*)d_in[iW2];
    const float* b2 = (const float*)d_in[ib2];
    const int*   c0  = (const int*)d_in[ic0];
    const int*   c1  = (const int*)d_in[ic1];
    const int*   c2  = (const int*)d_in[ic2];
    const float* c0f = (const float*)d_in[ic0];
    const float* c2f = (const float*)d_in[ic2];

    float* zout  = (float*)d_out;                        // z: 640000 fp32 (head)
    float* recon = zout + (size_t)N_NODES * H2F;         // recon: 1e8 fp32 (400 MB)

    // Scratch inside the fp32 recon region: all dead before k_decoder, which
    // overwrites every recon element afterwards.
    char* scratch = (char*)recon;
    size_t o = 0;
    auto alloc = [&](size_t bytes) { size_t p = o; o += (bytes + 255) & ~(size_t)255; return p; };
    int*   sel  = (int*)  (scratch + alloc(256));
    float* sup1 = (float*)(scratch + alloc((size_t)N_NODES * H1F * 4));
    float* agg1 = (float*)(scratch + alloc((size_t)N_NODES * H1F * 4));
    float* sup2 = (float*)(scratch + alloc((size_t)N_NODES * H2F * 4));
    // ~23 MB << 400 MB

    k_classify<<<1, 1024, 0, stream>>>(c0, c2, sel);

    // Layer 1
    k_gemm1<<<N_NODES / 8, 256, 0, stream>>>(x, W1, sup1);
    hipMemsetAsync(agg1, 0, (size_t)N_NODES * H1F * 4, stream);
    k_scatter<<<N_EDGES, H1F, 0, stream>>>(sup1, c0, c1, c2, c0f, c2f, sel, agg1, H1F);
    k_bias_relu<<<(N_NODES * H1F + 255) / 256, 256, 0, stream>>>(agg1, b1, N_NODES * H1F, H1F - 1);

    // Layer 2 — accumulate directly into the fp32 z slot of d_out
    k_gemm2<<<N_NODES / 4, 64, 0, stream>>>(agg1, W2, sup2);
    hipMemsetAsync(zout, 0, (size_t)N_NODES * H2F * 4, stream);
    k_scatter<<<N_EDGES, H2F, 0, stream>>>(sup2, c0, c1, c2, c0f, c2f, sel, zout, H2F);
    k_bias_relu<<<(N_NODES * H2F + 255) / 256, 256, 0, stream>>>(zout, b2, N_NODES * H2F, H2F - 1);

    // Decoder
    dim3 dgrid((N_NODES + 63) / 64, (N_NODES + 63) / 64);
    k_decoder<<<dgrid, 256, 0, stream>>>(zout, recon);
}

// Round 10
// 740.507 us; speedup vs baseline: 1.3101x; 1.3101x over previous
//
#include <hip/hip_runtime.h>

#define N_NODES 10000
#define N_EDGES 320000
#define IN_F    512
#define H1F     256
#define H2F     64

// ---------- edge-order classify: sel=0 dict (ew,src,dst), sel=1 alpha (dst,src,ew) ----------
__global__ __launch_bounds__(1024) void k_classify(const int* __restrict__ c0,
                                                   const int* __restrict__ c2,
                                                   int* __restrict__ sel) {
    __shared__ int cnt0, cnt2;
    if (threadIdx.x == 0) { cnt0 = 0; cnt2 = 0; }
    __syncthreads();
    int v0 = c0[threadIdx.x];
    int v2 = c2[threadIdx.x];
    if (v0 >= 0 && v0 < N_NODES) atomicAdd(&cnt0, 1);
    if (v2 >= 0 && v2 < N_NODES) atomicAdd(&cnt2, 1);
    __syncthreads();
    if (threadIdx.x == 0) *sel = (cnt0 > 900 && cnt2 <= 900) ? 1 : 0;
}

// ---------- CSR build: histogram -> scan -> bucket (packed src+w) ----------
__global__ __launch_bounds__(256) void k_hist(const int* __restrict__ c0,
                                              const int* __restrict__ c2,
                                              const int* __restrict__ sel,
                                              int* __restrict__ deg) {
    int e = blockIdx.x * 256 + threadIdx.x;
    if (e >= N_EDGES) return;
    int dst = (*sel) ? c0[e] : c2[e];
    if ((unsigned)dst < N_NODES) atomicAdd(&deg[dst], 1);
}

__global__ __launch_bounds__(1024) void k_scan(const int* __restrict__ deg,
                                               int* __restrict__ off,
                                               int* __restrict__ cursor) {
    __shared__ int part[1024];
    int t = threadIdx.x;
    const int chunk = (N_NODES + 1023) / 1024;  // 10
    int begin = t * chunk;
    int end = begin + chunk; if (end > N_NODES) end = N_NODES;
    if (begin > N_NODES) begin = N_NODES;
    int s = 0;
    for (int i = begin; i < end; ++i) s += deg[i];
    part[t] = s;
    __syncthreads();
    for (int o = 1; o < 1024; o <<= 1) {
        int v = (t >= o) ? part[t - o] : 0;
        __syncthreads();
        part[t] += v;
        __syncthreads();
    }
    int base = (t == 0) ? 0 : part[t - 1];
    for (int i = begin; i < end; ++i) {
        off[i] = base; cursor[i] = base; base += deg[i];
    }
    if (t == 1023) off[N_NODES] = part[1023];
}

__global__ __launch_bounds__(256) void k_bucket(const int* __restrict__ c0,
                                                const int* __restrict__ c1,
                                                const int* __restrict__ c2,
                                                const float* __restrict__ c0f,
                                                const float* __restrict__ c2f,
                                                const int* __restrict__ sel,
                                                int* __restrict__ cursor,
                                                int* __restrict__ srcp,
                                                float* __restrict__ wp) {
    int e = blockIdx.x * 256 + threadIdx.x;
    if (e >= N_EDGES) return;
    int s = *sel;
    int src = c1[e];
    int dst = s ? c0[e] : c2[e];
    float w = s ? c2f[e] : c0f[e];
    if ((unsigned)src >= N_NODES || (unsigned)dst >= N_NODES) return;
    int p = atomicAdd(&cursor[dst], 1);
    srcp[p] = src;
    wp[p] = w;
}

// ---------- GEMM1: sup1[10000,256] = x @ W1, 8 nodes/block ----------
__global__ __launch_bounds__(256) void k_gemm1(const float* __restrict__ x,
                                               const float* __restrict__ W1,
                                               float* __restrict__ sup1) {
    __shared__ float xs[IN_F][8];
    int nb = blockIdx.x * 8;
    int t = threadIdx.x;
    {
        int n  = t & 7;
        int k0 = (t >> 3) * 16;
        const float* xr = x + (size_t)(nb + n) * IN_F + k0;
        #pragma unroll
        for (int c = 0; c < 16; c += 4) {
            float4 v = *(const float4*)(xr + c);
            xs[k0 + c + 0][n] = v.x;
            xs[k0 + c + 1][n] = v.y;
            xs[k0 + c + 2][n] = v.z;
            xs[k0 + c + 3][n] = v.w;
        }
    }
    __syncthreads();
    int f = t;
    float acc[8] = {0.f,0.f,0.f,0.f,0.f,0.f,0.f,0.f};
    #pragma unroll 8
    for (int k = 0; k < IN_F; ++k) {
        float w = W1[(size_t)k * H1F + f];
        float4 a = *(const float4*)&xs[k][0];
        float4 b = *(const float4*)&xs[k][4];
        acc[0] += a.x * w; acc[1] += a.y * w; acc[2] += a.z * w; acc[3] += a.w * w;
        acc[4] += b.x * w; acc[5] += b.y * w; acc[6] += b.z * w; acc[7] += b.w * w;
    }
    #pragma unroll
    for (int n = 0; n < 8; ++n)
        sup1[(size_t)(nb + n) * H1F + f] = acc[n];
}

// ---------- agg1 gather: h1[v,f] = relu(b1[f] + sum_i w * sup1[src,f]) ----------
__global__ __launch_bounds__(256) void k_agg1(const float* __restrict__ sup1,
                                              const int* __restrict__ off,
                                              const int* __restrict__ srcp,
                                              const float* __restrict__ wp,
                                              const float* __restrict__ b1,
                                              float* __restrict__ h1) {
    int node = blockIdx.x;
    int f = threadIdx.x;
    int s = off[node], e = off[node + 1];
    float acc = 0.f;
    for (int i = s; i < e; ++i) {
        float w = wp[i];
        int src = srcp[i];
        acc += w * sup1[(size_t)src * H1F + f];   // 1 KB coalesced row read (L2/L3 resident)
    }
    h1[(size_t)node * H1F + f] = fmaxf(acc + b1[f], 0.f);
}

// ---------- GEMM2: sup2[10000,64] = h1 @ W2, 4 nodes/block ----------
__global__ __launch_bounds__(64) void k_gemm2(const float* __restrict__ h1,
                                              const float* __restrict__ W2,
                                              float* __restrict__ sup2) {
    __shared__ float hs[H1F][4];
    int nb = blockIdx.x * 4;
    int t = threadIdx.x;
    {
        int n  = t & 3;
        int k0 = (t >> 2) * 16;
        const float* hr = h1 + (size_t)(nb + n) * H1F + k0;
        #pragma unroll
        for (int c = 0; c < 16; c += 4) {
            float4 v = *(const float4*)(hr + c);
            hs[k0 + c + 0][n] = v.x;
            hs[k0 + c + 1][n] = v.y;
            hs[k0 + c + 2][n] = v.z;
            hs[k0 + c + 3][n] = v.w;
        }
    }
    __syncthreads();
    int f = t;
    float acc[4] = {0.f,0.f,0.f,0.f};
    #pragma unroll 8
    for (int k = 0; k < H1F; ++k) {
        float w = W2[(size_t)k * H2F + f];
        float4 a = *(const float4*)&hs[k][0];
        acc[0] += a.x * w; acc[1] += a.y * w; acc[2] += a.z * w; acc[3] += a.w * w;
    }
    #pragma unroll
    for (int n = 0; n < 4; ++n)
        sup2[(size_t)(nb + n) * H2F + f] = acc[n];
}

// ---------- agg2 gather: z[v,f] = relu(b2[f] + sum_i w * sup2[src,f]) -> zout ----------
__global__ __launch_bounds__(64) void k_agg2(const float* __restrict__ sup2,
                                             const int* __restrict__ off,
                                             const int* __restrict__ srcp,
                                             const float* __restrict__ wp,
                                             const float* __restrict__ b2,
                                             float* __restrict__ zout) {
    int node = blockIdx.x;
    int f = threadIdx.x;
    int s = off[node], e = off[node + 1];
    float acc = 0.f;
    for (int i = s; i < e; ++i) {
        float w = wp[i];
        int src = srcp[i];
        acc += w * sup2[(size_t)src * H2F + f];   // 256 B coalesced row read
    }
    zout[(size_t)node * H2F + f] = fmaxf(acc + b2[f], 0.f);
}

// ---------- decoder: recon = sigmoid(z @ z^T), fp32, 64x64 tile ----------
__global__ __launch_bounds__(256) void k_decoder(const float* __restrict__ zf,
                                                 float* __restrict__ recon) {
    __shared__ float As[H2F][68];
    __shared__ float Bs[H2F][68];
    int i0 = blockIdx.y * 64, j0 = blockIdx.x * 64;
    int t = threadIdx.x;
    int li = t & 63;
    int kq = t >> 6;
    #pragma unroll
    for (int rep = 0; rep < 4; ++rep) {
        int k0 = (kq + rep * 4) * 4;
        float4 va = make_float4(0.f, 0.f, 0.f, 0.f);
        float4 vb = make_float4(0.f, 0.f, 0.f, 0.f);
        if (i0 + li < N_NODES) va = *(const float4*)&zf[(size_t)(i0 + li) * H2F + k0];
        if (j0 + li < N_NODES) vb = *(const float4*)&zf[(size_t)(j0 + li) * H2F + k0];
        As[k0 + 0][li] = va.x; As[k0 + 1][li] = va.y; As[k0 + 2][li] = va.z; As[k0 + 3][li] = va.w;
        Bs[k0 + 0][li] = vb.x; Bs[k0 + 1][li] = vb.y; Bs[k0 + 2][li] = vb.z; Bs[k0 + 3][li] = vb.w;
    }
    __syncthreads();

    int tx = t & 15, ty = t >> 4;
    float acc[4][4] = {{0.f}};
    #pragma unroll 4
    for (int k = 0; k < H2F; ++k) {
        float a0 = As[k][ty * 4 + 0], a1 = As[k][ty * 4 + 1];
        float a2 = As[k][ty * 4 + 2], a3 = As[k][ty * 4 + 3];
        float b0 = Bs[k][tx * 4 + 0], b1 = Bs[k][tx * 4 + 1];
        float b2 = Bs[k][tx * 4 + 2], b3 = Bs[k][tx * 4 + 3];
        acc[0][0] += a0 * b0; acc[0][1] += a0 * b1; acc[0][2] += a0 * b2; acc[0][3] += a0 * b3;
        acc[1][0] += a1 * b0; acc[1][1] += a1 * b1; acc[1][2] += a1 * b2; acc[1][3] += a1 * b3;
        acc[2][0] += a2 * b0; acc[2][1] += a2 * b1; acc[2][2] += a2 * b2; acc[2][3] += a2 * b3;
        acc[3][0] += a3 * b0; acc[3][1] += a3 * b1; acc[3][2] += a3 * b2; acc[3][3] += a3 * b3;
    }

    #pragma unroll
    for (int ii = 0; ii < 4; ++ii) {
        int row = i0 + ty * 4 + ii;
        if (row >= N_NODES) continue;
        int col = j0 + tx * 4;
        float o4[4];
        #pragma unroll
        for (int jj = 0; jj < 4; ++jj) {
            float s = acc[ii][jj];
            o4[jj] = 1.0f / (1.0f + __expf(-s));
        }
        size_t base = (size_t)row * N_NODES + col;
        if (col + 4 <= N_NODES) {
            *(float4*)(recon + base) = make_float4(o4[0], o4[1], o4[2], o4[3]);
        } else {
            for (int jj = 0; jj < 4; ++jj)
                if (col + jj < N_NODES) recon[base + jj] = o4[jj];
        }
    }
}

extern "C" void kernel_launch(void* const* d_in, const int* in_sizes, int n_in,
                              void* d_out, int out_size, void* d_ws, size_t ws_size,
                              hipStream_t stream) {
    int ix = -1, iW1 = -1, ib1 = -1, iW2 = -1, ib2 = -1, ic0 = -1, ic1 = -1, ic2 = -1;
    for (int i = 0; i < n_in; ++i) {
        int s = in_sizes[i];
        if      (s == N_NODES * IN_F) ix = i;
        else if (s == IN_F * H1F)     iW1 = i;
        else if (s == H1F)            ib1 = i;
        else if (s == H1F * H2F)     iW2 = i;
        else if (s == H2F)            ib2 = i;
        else if (s == N_EDGES) { if (ic0 < 0) ic0 = i; else if (ic1 < 0) ic1 = i; else ic2 = i; }
    }
    if (ix < 0 || iW1 < 0 || ib1 < 0 || iW2 < 0 || ib2 < 0 || ic0 < 0 || ic1 < 0 || ic2 < 0) {
        ix = 0; iW1 = 1; ib1 = 2; iW2 = 3; ib2 = 4; ic0 = 5; ic1 = 6; ic2 = 7;
    }
    const float* x  = (const float*)d_in[ix];
    const float* W1 = (const float*)d_in[iW1];
    const float* b1 = (const float*)d_in[ib1];
    const float* W2 = (const float*)d_in[iW2];
    const float* b2 = (const float*)d_in[ib2];
    const int*   c0  = (const int*)d_in[ic0];
    const int*   c1  = (const int*)d_in[ic1];
    const int*   c2  = (const int*)d_in[ic2];
    const float* c0f = (const float*)d_in[ic0];
    const float* c2f = (const float*)d_in[ic2];

    float* zout  = (float*)d_out;                        // z: 640000 fp32
    float* recon = zout + (size_t)N_NODES * H2F;         // recon: 1e8 fp32 (400 MB)

    // Scratch inside fp32 recon region (dead before k_decoder overwrites all of it).
    char* scratch = (char*)recon;
    size_t o = 0;
    auto alloc = [&](size_t bytes) { size_t p = o; o += (bytes + 255) & ~(size_t)255; return p; };
    int*   sel    = (int*)  (scratch + alloc(256));
    int*   deg    = (int*)  (scratch + alloc((size_t)N_NODES * 4));
    int*   off    = (int*)  (scratch + alloc((size_t)(N_NODES + 1) * 4));
    int*   cursor = (int*)  (scratch + alloc((size_t)N_NODES * 4));
    int*   srcp   = (int*)  (scratch + alloc((size_t)N_EDGES * 4));
    float* wp     = (float*)(scratch + alloc((size_t)N_EDGES * 4));
    float* sup1   = (float*)(scratch + alloc((size_t)N_NODES * H1F * 4));
    float* h1     = (float*)(scratch + alloc((size_t)N_NODES * H1F * 4));
    float* sup2   = (float*)(scratch + alloc((size_t)N_NODES * H2F * 4));
    // ~26 MB << 400 MB

    k_classify<<<1, 1024, 0, stream>>>(c0, c2, sel);

    // CSR build (runs concurrently-ish with gemm1 in-order; all tiny)
    hipMemsetAsync(deg, 0, (size_t)N_NODES * 4, stream);
    k_hist  <<<(N_EDGES + 255) / 256, 256, 0, stream>>>(c0, c2, sel, deg);
    k_scan  <<<1, 1024, 0, stream>>>(deg, off, cursor);
    k_bucket<<<(N_EDGES + 255) / 256, 256, 0, stream>>>(c0, c1, c2, c0f, c2f, sel, cursor, srcp, wp);

    // Layer 1
    k_gemm1<<<N_NODES / 8, 256, 0, stream>>>(x, W1, sup1);
    k_agg1 <<<N_NODES, 256, 0, stream>>>(sup1, off, srcp, wp, b1, h1);

    // Layer 2
    k_gemm2<<<N_NODES / 4, 64, 0, stream>>>(h1, W2, sup2);
    k_agg2 <<<N_NODES, 64, 0, stream>>>(sup2, off, srcp, wp, b2, zout);

    // Decoder
    dim3 dgrid((N_NODES + 63) / 64, (N_NODES + 63) / 64);
    k_decoder<<<dgrid, 256, 0, stream>>>(zout, recon);
}

// Round 11
// 663.260 us; speedup vs baseline: 1.4627x; 1.1165x over previous
//
#include <hip/hip_runtime.h>

#define N_NODES 10000
#define N_EDGES 320000
#define IN_F    512
#define H1F     256
#define H2F     64

typedef __attribute__((ext_vector_type(8)))  short short8;   // 8 x bf16 (4 VGPRs)
typedef __attribute__((ext_vector_type(16))) float f32x16;   // MFMA 32x32 accumulator

__device__ __forceinline__ unsigned short f2bf(float f) {
    union { float fl; unsigned int i; } v; v.fl = f;
    unsigned int x = v.i;
    return (unsigned short)((x + 0x7fffu + ((x >> 16) & 1u)) >> 16);
}

// ---------- edge-order classify: sel=0 dict (ew,src,dst), sel=1 alpha (dst,src,ew) ----------
__global__ __launch_bounds__(1024) void k_classify(const int* __restrict__ c0,
                                                   const int* __restrict__ c2,
                                                   int* __restrict__ sel) {
    __shared__ int cnt0, cnt2;
    if (threadIdx.x == 0) { cnt0 = 0; cnt2 = 0; }
    __syncthreads();
    int v0 = c0[threadIdx.x];
    int v2 = c2[threadIdx.x];
    if (v0 >= 0 && v0 < N_NODES) atomicAdd(&cnt0, 1);
    if (v2 >= 0 && v2 < N_NODES) atomicAdd(&cnt2, 1);
    __syncthreads();
    if (threadIdx.x == 0) *sel = (cnt0 > 900 && cnt2 <= 900) ? 1 : 0;
}

// ---------- CSR build: histogram -> scan -> bucket (packed src+w) ----------
__global__ __launch_bounds__(256) void k_hist(const int* __restrict__ c0,
                                              const int* __restrict__ c2,
                                              const int* __restrict__ sel,
                                              int* __restrict__ deg) {
    int e = blockIdx.x * 256 + threadIdx.x;
    if (e >= N_EDGES) return;
    int dst = (*sel) ? c0[e] : c2[e];
    if ((unsigned)dst < N_NODES) atomicAdd(&deg[dst], 1);
}

__global__ __launch_bounds__(1024) void k_scan(const int* __restrict__ deg,
                                               int* __restrict__ off,
                                               int* __restrict__ cursor) {
    __shared__ int part[1024];
    int t = threadIdx.x;
    const int chunk = (N_NODES + 1023) / 1024;  // 10
    int begin = t * chunk;
    int end = begin + chunk; if (end > N_NODES) end = N_NODES;
    if (begin > N_NODES) begin = N_NODES;
    int s = 0;
    for (int i = begin; i < end; ++i) s += deg[i];
    part[t] = s;
    __syncthreads();
    for (int o = 1; o < 1024; o <<= 1) {
        int v = (t >= o) ? part[t - o] : 0;
        __syncthreads();
        part[t] += v;
        __syncthreads();
    }
    int base = (t == 0) ? 0 : part[t - 1];
    for (int i = begin; i < end; ++i) {
        off[i] = base; cursor[i] = base; base += deg[i];
    }
    if (t == 1023) off[N_NODES] = part[1023];
}

__global__ __launch_bounds__(256) void k_bucket(const int* __restrict__ c0,
                                                const int* __restrict__ c1,
                                                const int* __restrict__ c2,
                                                const float* __restrict__ c0f,
                                                const float* __restrict__ c2f,
                                                const int* __restrict__ sel,
                                                int* __restrict__ cursor,
                                                int* __restrict__ srcp,
                                                float* __restrict__ wp) {
    int e = blockIdx.x * 256 + threadIdx.x;
    if (e >= N_EDGES) return;
    int s = *sel;
    int src = c1[e];
    int dst = s ? c0[e] : c2[e];
    float w = s ? c2f[e] : c0f[e];
    if ((unsigned)src >= N_NODES || (unsigned)dst >= N_NODES) return;
    int p = atomicAdd(&cursor[dst], 1);
    srcp[p] = src;
    wp[p] = w;
}

// ---------- GEMM1: sup1[10000,256] = x @ W1, 8 nodes/block ----------
__global__ __launch_bounds__(256) void k_gemm1(const float* __restrict__ x,
                                               const float* __restrict__ W1,
                                               float* __restrict__ sup1) {
    __shared__ float xs[IN_F][8];
    int nb = blockIdx.x * 8;
    int t = threadIdx.x;
    {
        int n  = t & 7;
        int k0 = (t >> 3) * 16;
        const float* xr = x + (size_t)(nb + n) * IN_F + k0;
        #pragma unroll
        for (int c = 0; c < 16; c += 4) {
            float4 v = *(const float4*)(xr + c);
            xs[k0 + c + 0][n] = v.x;
            xs[k0 + c + 1][n] = v.y;
            xs[k0 + c + 2][n] = v.z;
            xs[k0 + c + 3][n] = v.w;
        }
    }
    __syncthreads();
    int f = t;
    float acc[8] = {0.f,0.f,0.f,0.f,0.f,0.f,0.f,0.f};
    #pragma unroll 8
    for (int k = 0; k < IN_F; ++k) {
        float w = W1[(size_t)k * H1F + f];
        float4 a = *(const float4*)&xs[k][0];
        float4 b = *(const float4*)&xs[k][4];
        acc[0] += a.x * w; acc[1] += a.y * w; acc[2] += a.z * w; acc[3] += a.w * w;
        acc[4] += b.x * w; acc[5] += b.y * w; acc[6] += b.z * w; acc[7] += b.w * w;
    }
    #pragma unroll
    for (int n = 0; n < 8; ++n)
        sup1[(size_t)(nb + n) * H1F + f] = acc[n];
}

// ---------- agg1 gather: h1[v,f] = relu(b1[f] + sum_i w * sup1[src,f]) ----------
__global__ __launch_bounds__(256) void k_agg1(const float* __restrict__ sup1,
                                              const int* __restrict__ off,
                                              const int* __restrict__ srcp,
                                              const float* __restrict__ wp,
                                              const float* __restrict__ b1,
                                              float* __restrict__ h1) {
    int node = blockIdx.x;
    int f = threadIdx.x;
    int s = off[node], e = off[node + 1];
    float acc = 0.f;
    for (int i = s; i < e; ++i) {
        float w = wp[i];
        int src = srcp[i];
        acc += w * sup1[(size_t)src * H1F + f];
    }
    h1[(size_t)node * H1F + f] = fmaxf(acc + b1[f], 0.f);
}

// ---------- GEMM2: sup2[10000,64] = h1 @ W2, 4 nodes/block ----------
__global__ __launch_bounds__(64) void k_gemm2(const float* __restrict__ h1,
                                              const float* __restrict__ W2,
                                              float* __restrict__ sup2) {
    __shared__ float hs[H1F][4];
    int nb = blockIdx.x * 4;
    int t = threadIdx.x;
    {
        int n  = t & 3;
        int k0 = (t >> 2) * 16;
        const float* hr = h1 + (size_t)(nb + n) * H1F + k0;
        #pragma unroll
        for (int c = 0; c < 16; c += 4) {
            float4 v = *(const float4*)(hr + c);
            hs[k0 + c + 0][n] = v.x;
            hs[k0 + c + 1][n] = v.y;
            hs[k0 + c + 2][n] = v.z;
            hs[k0 + c + 3][n] = v.w;
        }
    }
    __syncthreads();
    int f = t;
    float acc[4] = {0.f,0.f,0.f,0.f};
    #pragma unroll 8
    for (int k = 0; k < H1F; ++k) {
        float w = W2[(size_t)k * H2F + f];
        float4 a = *(const float4*)&hs[k][0];
        acc[0] += a.x * w; acc[1] += a.y * w; acc[2] += a.z * w; acc[3] += a.w * w;
    }
    #pragma unroll
    for (int n = 0; n < 4; ++n)
        sup2[(size_t)(nb + n) * H2F + f] = acc[n];
}

// ---------- agg2 gather: z = relu(b2 + gather); writes fp32 z (d_out) + bf16 zb (ws) ----------
__global__ __launch_bounds__(64) void k_agg2(const float* __restrict__ sup2,
                                             const int* __restrict__ off,
                                             const int* __restrict__ srcp,
                                             const float* __restrict__ wp,
                                             const float* __restrict__ b2,
                                             float* __restrict__ zout,
                                             unsigned short* __restrict__ zb) {
    int node = blockIdx.x;
    int f = threadIdx.x;
    int s = off[node], e = off[node + 1];
    float acc = 0.f;
    for (int i = s; i < e; ++i) {
        float w = wp[i];
        int src = srcp[i];
        acc += w * sup2[(size_t)src * H2F + f];
    }
    acc = fmaxf(acc + b2[f], 0.f);
    zout[(size_t)node * H2F + f] = acc;
    zb[(size_t)node * H2F + f] = f2bf(acc);
}

// ---------- decoder: recon = sigmoid(zb @ zb^T) via bf16 MFMA 32x32x16 ----------
// Gram-matrix property: A-frag and B-frag of Z rows have IDENTICAL lane layouts
// (any consistent k-permutation cancels in sum_k), so only the C/D layout matters:
// col = lane&31, row = (reg&3) + 8*(reg>>2) + 4*(lane>>5)   [HW-verified m74/m101]
__global__ __launch_bounds__(256) void k_decoder(const unsigned short* __restrict__ zb,
                                                 float* __restrict__ recon) {
    int t = threadIdx.x;
    int wave = t >> 6, lane = t & 63;
    int i0 = blockIdx.y * 64 + (wave >> 1) * 32;
    int j0 = blockIdx.x * 64 + (wave & 1) * 32;
    int r = lane & 31, half = lane >> 5;
    int arow = i0 + r, brow = j0 + r;

    short8 zero8 = {0,0,0,0,0,0,0,0};
    short8 a[4], b[4];
    #pragma unroll
    for (int s = 0; s < 4; ++s) {
        a[s] = (arow < N_NODES) ? *(const short8*)(zb + (size_t)arow * H2F + s * 16 + half * 8)
                                : zero8;
        b[s] = (brow < N_NODES) ? *(const short8*)(zb + (size_t)brow * H2F + s * 16 + half * 8)
                                : zero8;
    }

    f32x16 acc;
    #pragma unroll
    for (int i = 0; i < 16; ++i) acc[i] = 0.f;
    #pragma unroll
    for (int s = 0; s < 4; ++s)
        acc = __builtin_amdgcn_mfma_f32_32x32x16_bf16(a[s], b[s], acc, 0, 0, 0);

    #pragma unroll
    for (int rg = 0; rg < 16; ++rg) {
        int row = i0 + (rg & 3) + 8 * (rg >> 2) + 4 * half;
        int col = j0 + r;
        if (row < N_NODES && col < N_NODES) {
            float sv = acc[rg];                      // >= 0 (z >= 0)
            recon[(size_t)row * N_NODES + col] = 1.0f / (1.0f + __expf(-sv));
        }
    }
}

extern "C" void kernel_launch(void* const* d_in, const int* in_sizes, int n_in,
                              void* d_out, int out_size, void* d_ws, size_t ws_size,
                              hipStream_t stream) {
    int ix = -1, iW1 = -1, ib1 = -1, iW2 = -1, ib2 = -1, ic0 = -1, ic1 = -1, ic2 = -1;
    for (int i = 0; i < n_in; ++i) {
        int s = in_sizes[i];
        if      (s == N_NODES * IN_F) ix = i;
        else if (s == IN_F * H1F)     iW1 = i;
        else if (s == H1F)            ib1 = i;
        else if (s == H1F * H2F)      iW2 = i;
        else if (s == H2F)            ib2 = i;
        else if (s == N_EDGES) { if (ic0 < 0) ic0 = i; else if (ic1 < 0) ic1 = i; else ic2 = i; }
    }
    if (ix < 0 || iW1 < 0 || ib1 < 0 || iW2 < 0 || ib2 < 0 || ic0 < 0 || ic1 < 0 || ic2 < 0) {
        ix = 0; iW1 = 1; ib1 = 2; iW2 = 3; ib2 = 4; ic0 = 5; ic1 = 6; ic2 = 7;
    }
    const float* x  = (const float*)d_in[ix];
    const float* W1 = (const float*)d_in[iW1];
    const float* b1 = (const float*)d_in[ib1];
    const float* W2 = (const float*)d_in[iW2];
    const float* b2 = (const float*)d_in[ib2];
    const int*   c0  = (const int*)d_in[ic0];
    const int*   c1  = (const int*)d_in[ic1];
    const int*   c2  = (const int*)d_in[ic2];
    const float* c0f = (const float*)d_in[ic0];
    const float* c2f = (const float*)d_in[ic2];

    float* zout  = (float*)d_out;                        // z: 640000 fp32
    float* recon = zout + (size_t)N_NODES * H2F;         // recon: 1e8 fp32 (400 MB)

    // zb lives in d_ws (~1.6 GB per fill counters) — must NOT be in the recon
    // region because k_decoder reads it while overwriting recon.
    unsigned short* zb = (unsigned short*)d_ws;          // 10000*64 bf16 = 1.28 MB

    // Remaining scratch inside fp32 recon region (all dead before k_decoder).
    char* scratch = (char*)recon;
    size_t o = 0;
    auto alloc = [&](size_t bytes) { size_t p = o; o += (bytes + 255) & ~(size_t)255; return p; };
    int*   sel    = (int*)  (scratch + alloc(256));
    int*   deg    = (int*)  (scratch + alloc((size_t)N_NODES * 4));
    int*   off    = (int*)  (scratch + alloc((size_t)(N_NODES + 1) * 4));
    int*   cursor = (int*)  (scratch + alloc((size_t)N_NODES * 4));
    int*   srcp   = (int*)  (scratch + alloc((size_t)N_EDGES * 4));
    float* wp     = (float*)(scratch + alloc((size_t)N_EDGES * 4));
    float* sup1   = (float*)(scratch + alloc((size_t)N_NODES * H1F * 4));
    float* h1     = (float*)(scratch + alloc((size_t)N_NODES * H1F * 4));
    float* sup2   = (float*)(scratch + alloc((size_t)N_NODES * H2F * 4));

    k_classify<<<1, 1024, 0, stream>>>(c0, c2, sel);

    hipMemsetAsync(deg, 0, (size_t)N_NODES * 4, stream);
    k_hist  <<<(N_EDGES + 255) / 256, 256, 0, stream>>>(c0, c2, sel, deg);
    k_scan  <<<1, 1024, 0, stream>>>(deg, off, cursor);
    k_bucket<<<(N_EDGES + 255) / 256, 256, 0, stream>>>(c0, c1, c2, c0f, c2f, sel, cursor, srcp, wp);

    k_gemm1<<<N_NODES / 8, 256, 0, stream>>>(x, W1, sup1);
    k_agg1 <<<N_NODES, 256, 0, stream>>>(sup1, off, srcp, wp, b1, h1);

    k_gemm2<<<N_NODES / 4, 64, 0, stream>>>(h1, W2, sup2);
    k_agg2 <<<N_NODES, 64, 0, stream>>>(sup2, off, srcp, wp, b2, zout, zb);

    dim3 dgrid((N_NODES + 63) / 64, (N_NODES + 63) / 64);
    k_decoder<<<dgrid, 256, 0, stream>>>(zb, recon);
}

// Round 12
// 655.484 us; speedup vs baseline: 1.4801x; 1.0119x over previous
//
#include <hip/hip_runtime.h>

#define N_NODES 10000
#define N_EDGES 320000
#define IN_F    512
#define H1F     256
#define H2F     64

typedef __attribute__((ext_vector_type(8)))  short short8;   // 8 x bf16 (4 VGPRs)
typedef __attribute__((ext_vector_type(16))) float f32x16;   // MFMA 32x32 accumulator

__device__ __forceinline__ unsigned short f2bf(float f) {
    union { float fl; unsigned int i; } v; v.fl = f;
    unsigned int x = v.i;
    return (unsigned short)((x + 0x7fffu + ((x >> 16) & 1u)) >> 16);
}
__device__ __forceinline__ float bf2f(unsigned short u) {
    union { unsigned int i; float f; } v; v.i = ((unsigned int)u) << 16; return v.f;
}

// ---------- classify edge-array order + zero deg (fused) ----------
// sel=0 dict (ew,src,dst), sel=1 alpha (dst,src,ew)
__global__ __launch_bounds__(1024) void k_classify(const int* __restrict__ c0,
                                                   const int* __restrict__ c2,
                                                   int* __restrict__ sel,
                                                   int* __restrict__ deg) {
    __shared__ int cnt0, cnt2;
    int t = threadIdx.x;
    if (t == 0) { cnt0 = 0; cnt2 = 0; }
    // zero deg while we're here (saves a memset dispatch)
    for (int i = t; i < N_NODES; i += 1024) deg[i] = 0;
    __syncthreads();
    int v0 = c0[t];
    int v2 = c2[t];
    if (v0 >= 0 && v0 < N_NODES) atomicAdd(&cnt0, 1);
    if (v2 >= 0 && v2 < N_NODES) atomicAdd(&cnt2, 1);
    __syncthreads();
    if (t == 0) *sel = (cnt0 > 900 && cnt2 <= 900) ? 1 : 0;
}

// ---------- CSR build: histogram -> scan -> bucket (packed src+w) ----------
__global__ __launch_bounds__(256) void k_hist(const int* __restrict__ c0,
                                              const int* __restrict__ c2,
                                              const int* __restrict__ sel,
                                              int* __restrict__ deg) {
    int e = blockIdx.x * 256 + threadIdx.x;
    if (e >= N_EDGES) return;
    int dst = (*sel) ? c0[e] : c2[e];
    if ((unsigned)dst < N_NODES) atomicAdd(&deg[dst], 1);
}

__global__ __launch_bounds__(1024) void k_scan(const int* __restrict__ deg,
                                               int* __restrict__ off,
                                               int* __restrict__ cursor) {
    __shared__ int part[1024];
    int t = threadIdx.x;
    const int chunk = (N_NODES + 1023) / 1024;  // 10
    int begin = t * chunk;
    int end = begin + chunk; if (end > N_NODES) end = N_NODES;
    if (begin > N_NODES) begin = N_NODES;
    int s = 0;
    for (int i = begin; i < end; ++i) s += deg[i];
    part[t] = s;
    __syncthreads();
    for (int o = 1; o < 1024; o <<= 1) {
        int v = (t >= o) ? part[t - o] : 0;
        __syncthreads();
        part[t] += v;
        __syncthreads();
    }
    int base = (t == 0) ? 0 : part[t - 1];
    for (int i = begin; i < end; ++i) {
        off[i] = base; cursor[i] = base; base += deg[i];
    }
    if (t == 1023) off[N_NODES] = part[1023];
}

__global__ __launch_bounds__(256) void k_bucket(const int* __restrict__ c0,
                                                const int* __restrict__ c1,
                                                const int* __restrict__ c2,
                                                const float* __restrict__ c0f,
                                                const float* __restrict__ c2f,
                                                const int* __restrict__ sel,
                                                int* __restrict__ cursor,
                                                int* __restrict__ srcp,
                                                float* __restrict__ wp) {
    int e = blockIdx.x * 256 + threadIdx.x;
    if (e >= N_EDGES) return;
    int s = *sel;
    int src = c1[e];
    int dst = s ? c0[e] : c2[e];
    float w = s ? c2f[e] : c0f[e];
    if ((unsigned)src >= N_NODES || (unsigned)dst >= N_NODES) return;
    int p = atomicAdd(&cursor[dst], 1);
    srcp[p] = src;
    wp[p] = w;
}

// ---------- GEMM1: sup1b[10000,256] (bf16) = x @ W1, 8 nodes/block ----------
__global__ __launch_bounds__(256) void k_gemm1(const float* __restrict__ x,
                                               const float* __restrict__ W1,
                                               unsigned short* __restrict__ sup1b) {
    __shared__ float xs[IN_F][8];
    int nb = blockIdx.x * 8;
    int t = threadIdx.x;
    {
        int n  = t & 7;
        int k0 = (t >> 3) * 16;
        const float* xr = x + (size_t)(nb + n) * IN_F + k0;
        #pragma unroll
        for (int c = 0; c < 16; c += 4) {
            float4 v = *(const float4*)(xr + c);
            xs[k0 + c + 0][n] = v.x;
            xs[k0 + c + 1][n] = v.y;
            xs[k0 + c + 2][n] = v.z;
            xs[k0 + c + 3][n] = v.w;
        }
    }
    __syncthreads();
    int f = t;
    float acc[8] = {0.f,0.f,0.f,0.f,0.f,0.f,0.f,0.f};
    #pragma unroll 8
    for (int k = 0; k < IN_F; ++k) {
        float w = W1[(size_t)k * H1F + f];
        float4 a = *(const float4*)&xs[k][0];
        float4 b = *(const float4*)&xs[k][4];
        acc[0] += a.x * w; acc[1] += a.y * w; acc[2] += a.z * w; acc[3] += a.w * w;
        acc[4] += b.x * w; acc[5] += b.y * w; acc[6] += b.z * w; acc[7] += b.w * w;
    }
    #pragma unroll
    for (int n = 0; n < 8; ++n)
        sup1b[(size_t)(nb + n) * H1F + f] = f2bf(acc[n]);
}

// ---------- agg1 gather (bf16 rows): h1[v,f] = relu(b1[f] + sum_i w * sup1[src,f]) ----------
__global__ __launch_bounds__(256) void k_agg1(const unsigned short* __restrict__ sup1b,
                                              const int* __restrict__ off,
                                              const int* __restrict__ srcp,
                                              const float* __restrict__ wp,
                                              const float* __restrict__ b1,
                                              float* __restrict__ h1) {
    int node = blockIdx.x;
    int f = threadIdx.x;
    int s = off[node], e = off[node + 1];
    float acc = 0.f;
    for (int i = s; i < e; ++i) {
        float w = wp[i];
        int src = srcp[i];
        acc += w * bf2f(sup1b[(size_t)src * H1F + f]);  // 512B coalesced row read
    }
    h1[(size_t)node * H1F + f] = fmaxf(acc + b1[f], 0.f);
}

// ---------- GEMM2: sup2[10000,64] = h1 @ W2, 4 nodes/block (fp32) ----------
__global__ __launch_bounds__(64) void k_gemm2(const float* __restrict__ h1,
                                              const float* __restrict__ W2,
                                              float* __restrict__ sup2) {
    __shared__ float hs[H1F][4];
    int nb = blockIdx.x * 4;
    int t = threadIdx.x;
    {
        int n  = t & 3;
        int k0 = (t >> 2) * 16;
        const float* hr = h1 + (size_t)(nb + n) * H1F + k0;
        #pragma unroll
        for (int c = 0; c < 16; c += 4) {
            float4 v = *(const float4*)(hr + c);
            hs[k0 + c + 0][n] = v.x;
            hs[k0 + c + 1][n] = v.y;
            hs[k0 + c + 2][n] = v.z;
            hs[k0 + c + 3][n] = v.w;
        }
    }
    __syncthreads();
    int f = t;
    float acc[4] = {0.f,0.f,0.f,0.f};
    #pragma unroll 8
    for (int k = 0; k < H1F; ++k) {
        float w = W2[(size_t)k * H2F + f];
        float4 a = *(const float4*)&hs[k][0];
        acc[0] += a.x * w; acc[1] += a.y * w; acc[2] += a.z * w; acc[3] += a.w * w;
    }
    #pragma unroll
    for (int n = 0; n < 4; ++n)
        sup2[(size_t)(nb + n) * H2F + f] = acc[n];
}

// ---------- agg2: z = relu(b2 + gather); fp32 z (d_out) + bf16 zb (ws) ----------
__global__ __launch_bounds__(64) void k_agg2(const float* __restrict__ sup2,
                                             const int* __restrict__ off,
                                             const int* __restrict__ srcp,
                                             const float* __restrict__ wp,
                                             const float* __restrict__ b2,
                                             float* __restrict__ zout,
                                             unsigned short* __restrict__ zb) {
    int node = blockIdx.x;
    int f = threadIdx.x;
    int s = off[node], e = off[node + 1];
    float acc = 0.f;
    for (int i = s; i < e; ++i) {
        float w = wp[i];
        int src = srcp[i];
        acc += w * sup2[(size_t)src * H2F + f];
    }
    acc = fmaxf(acc + b2[f], 0.f);
    zout[(size_t)node * H2F + f] = acc;
    zb[(size_t)node * H2F + f] = f2bf(acc);
}

// ---------- decoder: recon = sigmoid(zb @ zb^T) via bf16 MFMA 32x32x16 ----------
// Gram symmetry: A/B frags of Z rows share lane layouts; C/D layout HW-verified:
// col = lane&31, row = (reg&3) + 8*(reg>>2) + 4*(lane>>5)
__global__ __launch_bounds__(256) void k_decoder(const unsigned short* __restrict__ zb,
                                                 float* __restrict__ recon) {
    int t = threadIdx.x;
    int wave = t >> 6, lane = t & 63;
    int i0 = blockIdx.y * 64 + (wave >> 1) * 32;
    int j0 = blockIdx.x * 64 + (wave & 1) * 32;
    int r = lane & 31, half = lane >> 5;
    int arow = i0 + r, brow = j0 + r;

    short8 zero8 = {0,0,0,0,0,0,0,0};
    short8 a[4], b[4];
    #pragma unroll
    for (int s = 0; s < 4; ++s) {
        a[s] = (arow < N_NODES) ? *(const short8*)(zb + (size_t)arow * H2F + s * 16 + half * 8)
                                : zero8;
        b[s] = (brow < N_NODES) ? *(const short8*)(zb + (size_t)brow * H2F + s * 16 + half * 8)
                                : zero8;
    }

    f32x16 acc;
    #pragma unroll
    for (int i = 0; i < 16; ++i) acc[i] = 0.f;
    #pragma unroll
    for (int s = 0; s < 4; ++s)
        acc = __builtin_amdgcn_mfma_f32_32x32x16_bf16(a[s], b[s], acc, 0, 0, 0);

    #pragma unroll
    for (int rg = 0; rg < 16; ++rg) {
        int row = i0 + (rg & 3) + 8 * (rg >> 2) + 4 * half;
        int col = j0 + r;
        if (row < N_NODES && col < N_NODES) {
            float sv = acc[rg];
            recon[(size_t)row * N_NODES + col] = 1.0f / (1.0f + __expf(-sv));
        }
    }
}

extern "C" void kernel_launch(void* const* d_in, const int* in_sizes, int n_in,
                              void* d_out, int out_size, void* d_ws, size_t ws_size,
                              hipStream_t stream) {
    int ix = -1, iW1 = -1, ib1 = -1, iW2 = -1, ib2 = -1, ic0 = -1, ic1 = -1, ic2 = -1;
    for (int i = 0; i < n_in; ++i) {
        int s = in_sizes[i];
        if      (s == N_NODES * IN_F) ix = i;
        else if (s == IN_F * H1F)     iW1 = i;
        else if (s == H1F)            ib1 = i;
        else if (s == H1F * H2F)      iW2 = i;
        else if (s == H2F)            ib2 = i;
        else if (s == N_EDGES) { if (ic0 < 0) ic0 = i; else if (ic1 < 0) ic1 = i; else ic2 = i; }
    }
    if (ix < 0 || iW1 < 0 || ib1 < 0 || iW2 < 0 || ib2 < 0 || ic0 < 0 || ic1 < 0 || ic2 < 0) {
        ix = 0; iW1 = 1; ib1 = 2; iW2 = 3; ib2 = 4; ic0 = 5; ic1 = 6; ic2 = 7;
    }
    const float* x  = (const float*)d_in[ix];
    const float* W1 = (const float*)d_in[iW1];
    const float* b1 = (const float*)d_in[ib1];
    const float* W2 = (const float*)d_in[iW2];
    const float* b2 = (const float*)d_in[ib2];
    const int*   c0  = (const int*)d_in[ic0];
    const int*   c1  = (const int*)d_in[ic1];
    const int*   c2  = (const int*)d_in[ic2];
    const float* c0f = (const float*)d_in[ic0];
    const float* c2f = (const float*)d_in[ic2];

    float* zout  = (float*)d_out;                        // z: 640000 fp32
    float* recon = zout + (size_t)N_NODES * H2F;         // recon: 1e8 fp32 (400 MB)

    // zb in d_ws (decoder reads it while overwriting recon).
    unsigned short* zb = (unsigned short*)d_ws;          // 1.28 MB

    // Remaining scratch inside fp32 recon region (dead before k_decoder).
    char* scratch = (char*)recon;
    size_t o = 0;
    auto alloc = [&](size_t bytes) { size_t p = o; o += (bytes + 255) & ~(size_t)255; return p; };
    int*            sel    = (int*)           (scratch + alloc(256));
    int*            deg    = (int*)           (scratch + alloc((size_t)N_NODES * 4));
    int*            off    = (int*)           (scratch + alloc((size_t)(N_NODES + 1) * 4));
    int*            cursor = (int*)           (scratch + alloc((size_t)N_NODES * 4));
    int*            srcp   = (int*)           (scratch + alloc((size_t)N_EDGES * 4));
    float*          wp     = (float*)         (scratch + alloc((size_t)N_EDGES * 4));
    unsigned short* sup1b  = (unsigned short*)(scratch + alloc((size_t)N_NODES * H1F * 2));
    float*          h1     = (float*)         (scratch + alloc((size_t)N_NODES * H1F * 4));
    float*          sup2   = (float*)         (scratch + alloc((size_t)N_NODES * H2F * 4));

    k_classify<<<1, 1024, 0, stream>>>(c0, c2, sel, deg);
    k_hist  <<<(N_EDGES + 255) / 256, 256, 0, stream>>>(c0, c2, sel, deg);
    k_scan  <<<1, 1024, 0, stream>>>(deg, off, cursor);
    k_bucket<<<(N_EDGES + 255) / 256, 256, 0, stream>>>(c0, c1, c2, c0f, c2f, sel, cursor, srcp, wp);

    k_gemm1<<<N_NODES / 8, 256, 0, stream>>>(x, W1, sup1b);
    k_agg1 <<<N_NODES, 256, 0, stream>>>(sup1b, off, srcp, wp, b1, h1);

    k_gemm2<<<N_NODES / 4, 64, 0, stream>>>(h1, W2, sup2);
    k_agg2 <<<N_NODES, 64, 0, stream>>>(sup2, off, srcp, wp, b2, zout, zb);

    dim3 dgrid((N_NODES + 63) / 64, (N_NODES + 63) / 64);
    k_decoder<<<dgrid, 256, 0, stream>>>(zb, recon);
}

// Round 13
// 611.647 us; speedup vs baseline: 1.5862x; 1.0717x over previous
//
#include <hip/hip_runtime.h>

#define N_NODES 10000
#define N_EDGES 320000
#define IN_F    512
#define H1F     256
#define H2F     64

typedef __attribute__((ext_vector_type(8)))  short short8;   // 8 x bf16 (4 VGPRs)
typedef __attribute__((ext_vector_type(16))) float f32x16;   // MFMA 32x32 accumulator

__device__ __forceinline__ unsigned short f2bf(float f) {
    union { float fl; unsigned int i; } v; v.fl = f;
    unsigned int x = v.i;
    return (unsigned short)((x + 0x7fffu + ((x >> 16) & 1u)) >> 16);
}
__device__ __forceinline__ float bf2f(unsigned short u) {
    union { unsigned int i; float f; } v; v.i = ((unsigned int)u) << 16; return v.f;
}

// Per-edge order detection: in dict order (ew,src,dst) c0=float weight whose int
// reinterpretation is never in [0,N_NODES) (only denormals <1.4e-41 would be);
// in alpha order (dst,src,ew) c0=dst which always is. Exactly-0.0 weights would
// misroute, but such edges contribute 0 anyway.
__device__ __forceinline__ bool edge_is_alpha(int a0) {
    return (unsigned)a0 < N_NODES;
}

// ---------- CSR build: histogram -> scan -> bucket (packed (src,w)) ----------
__global__ __launch_bounds__(256) void k_hist(const int* __restrict__ c0,
                                              const int* __restrict__ c2,
                                              int* __restrict__ deg) {
    int e = blockIdx.x * 256 + threadIdx.x;
    if (e >= N_EDGES) return;
    int a0 = c0[e];
    int dst = edge_is_alpha(a0) ? a0 : c2[e];
    if ((unsigned)dst < N_NODES) atomicAdd(&deg[dst], 1);
}

__global__ __launch_bounds__(1024) void k_scan(const int* __restrict__ deg,
                                               int* __restrict__ off,
                                               int* __restrict__ cursor) {
    __shared__ int part[1024];
    int t = threadIdx.x;
    const int chunk = (N_NODES + 1023) / 1024;  // 10
    int begin = t * chunk;
    int end = begin + chunk; if (end > N_NODES) end = N_NODES;
    if (begin > N_NODES) begin = N_NODES;
    int s = 0;
    for (int i = begin; i < end; ++i) s += deg[i];
    part[t] = s;
    __syncthreads();
    for (int o = 1; o < 1024; o <<= 1) {
        int v = (t >= o) ? part[t - o] : 0;
        __syncthreads();
        part[t] += v;
        __syncthreads();
    }
    int base = (t == 0) ? 0 : part[t - 1];
    for (int i = begin; i < end; ++i) {
        off[i] = base; cursor[i] = base; base += deg[i];
    }
    if (t == 1023) off[N_NODES] = part[1023];
}

__global__ __launch_bounds__(256) void k_bucket(const int* __restrict__ c0,
                                                const int* __restrict__ c1,
                                                const int* __restrict__ c2,
                                                const float* __restrict__ c0f,
                                                const float* __restrict__ c2f,
                                                int* __restrict__ cursor,
                                                int2* __restrict__ ep) {
    int e = blockIdx.x * 256 + threadIdx.x;
    if (e >= N_EDGES) return;
    int a0 = c0[e];
    bool alpha = edge_is_alpha(a0);
    int src = c1[e];
    int dst = alpha ? a0 : c2[e];
    float w = alpha ? c2f[e] : c0f[e];
    if ((unsigned)src >= N_NODES || (unsigned)dst >= N_NODES) return;
    int p = atomicAdd(&cursor[dst], 1);
    ep[p] = make_int2(src, __float_as_int(w));
}

// ---------- GEMM1: sup1b[10000,256] (bf16) = x @ W1, 8 nodes/block ----------
__global__ __launch_bounds__(256) void k_gemm1(const float* __restrict__ x,
                                               const float* __restrict__ W1,
                                               unsigned short* __restrict__ sup1b) {
    __shared__ float xs[IN_F][8];
    int nb = blockIdx.x * 8;
    int t = threadIdx.x;
    {
        int n  = t & 7;
        int k0 = (t >> 3) * 16;
        const float* xr = x + (size_t)(nb + n) * IN_F + k0;
        #pragma unroll
        for (int c = 0; c < 16; c += 4) {
            float4 v = *(const float4*)(xr + c);
            xs[k0 + c + 0][n] = v.x;
            xs[k0 + c + 1][n] = v.y;
            xs[k0 + c + 2][n] = v.z;
            xs[k0 + c + 3][n] = v.w;
        }
    }
    __syncthreads();
    int f = t;
    float acc[8] = {0.f,0.f,0.f,0.f,0.f,0.f,0.f,0.f};
    #pragma unroll 8
    for (int k = 0; k < IN_F; ++k) {
        float w = W1[(size_t)k * H1F + f];
        float4 a = *(const float4*)&xs[k][0];
        float4 b = *(const float4*)&xs[k][4];
        acc[0] += a.x * w; acc[1] += a.y * w; acc[2] += a.z * w; acc[3] += a.w * w;
        acc[4] += b.x * w; acc[5] += b.y * w; acc[6] += b.z * w; acc[7] += b.w * w;
    }
    #pragma unroll
    for (int n = 0; n < 8; ++n)
        sup1b[(size_t)(nb + n) * H1F + f] = f2bf(acc[n]);
}

// ---------- agg1: LDS-staged edges, 4-way unrolled independent gathers ----------
__global__ __launch_bounds__(256) void k_agg1(const unsigned short* __restrict__ sup1b,
                                              const int* __restrict__ off,
                                              const int2* __restrict__ ep,
                                              const float* __restrict__ b1,
                                              float* __restrict__ h1) {
    __shared__ int2 eds[256];
    int node = blockIdx.x;
    int f = threadIdx.x;
    int s = off[node], e = off[node + 1];
    float a0 = 0.f, a1 = 0.f, a2 = 0.f, a3 = 0.f;
    for (int base = s; base < e; base += 256) {
        int n = e - base; if (n > 256) n = 256;
        __syncthreads();
        if (f < n) eds[f] = ep[base + f];
        __syncthreads();
        int j = 0;
        for (; j + 4 <= n; j += 4) {
            int2 e0 = eds[j], e1 = eds[j+1], e2 = eds[j+2], e3 = eds[j+3];
            a0 += __int_as_float(e0.y) * bf2f(sup1b[(size_t)e0.x * H1F + f]);
            a1 += __int_as_float(e1.y) * bf2f(sup1b[(size_t)e1.x * H1F + f]);
            a2 += __int_as_float(e2.y) * bf2f(sup1b[(size_t)e2.x * H1F + f]);
            a3 += __int_as_float(e3.y) * bf2f(sup1b[(size_t)e3.x * H1F + f]);
        }
        for (; j < n; ++j) {
            int2 e0 = eds[j];
            a0 += __int_as_float(e0.y) * bf2f(sup1b[(size_t)e0.x * H1F + f]);
        }
    }
    float acc = (a0 + a1) + (a2 + a3);
    h1[(size_t)node * H1F + f] = fmaxf(acc + b1[f], 0.f);
}

// ---------- GEMM2: sup2[10000,64] = h1 @ W2, 4 nodes/block (fp32) ----------
__global__ __launch_bounds__(64) void k_gemm2(const float* __restrict__ h1,
                                              const float* __restrict__ W2,
                                              float* __restrict__ sup2) {
    __shared__ float hs[H1F][4];
    int nb = blockIdx.x * 4;
    int t = threadIdx.x;
    {
        int n  = t & 3;
        int k0 = (t >> 2) * 16;
        const float* hr = h1 + (size_t)(nb + n) * H1F + k0;
        #pragma unroll
        for (int c = 0; c < 16; c += 4) {
            float4 v = *(const float4*)(hr + c);
            hs[k0 + c + 0][n] = v.x;
            hs[k0 + c + 1][n] = v.y;
            hs[k0 + c + 2][n] = v.z;
            hs[k0 + c + 3][n] = v.w;
        }
    }
    __syncthreads();
    int f = t;
    float acc[4] = {0.f,0.f,0.f,0.f};
    #pragma unroll 8
    for (int k = 0; k < H1F; ++k) {
        float w = W2[(size_t)k * H2F + f];
        float4 a = *(const float4*)&hs[k][0];
        acc[0] += a.x * w; acc[1] += a.y * w; acc[2] += a.z * w; acc[3] += a.w * w;
    }
    #pragma unroll
    for (int n = 0; n < 4; ++n)
        sup2[(size_t)(nb + n) * H2F + f] = acc[n];
}

// ---------- agg2: LDS-staged, unrolled; z fp32 (d_out) + bf16 zb (ws) ----------
__global__ __launch_bounds__(64) void k_agg2(const float* __restrict__ sup2,
                                             const int* __restrict__ off,
                                             const int2* __restrict__ ep,
                                             const float* __restrict__ b2,
                                             float* __restrict__ zout,
                                             unsigned short* __restrict__ zb) {
    __shared__ int2 eds[64];
    int node = blockIdx.x;
    int f = threadIdx.x;
    int s = off[node], e = off[node + 1];
    float a0 = 0.f, a1 = 0.f, a2 = 0.f, a3 = 0.f;
    for (int base = s; base < e; base += 64) {
        int n = e - base; if (n > 64) n = 64;
        __syncthreads();
        if (f < n) eds[f] = ep[base + f];
        __syncthreads();
        int j = 0;
        for (; j + 4 <= n; j += 4) {
            int2 e0 = eds[j], e1 = eds[j+1], e2 = eds[j+2], e3 = eds[j+3];
            a0 += __int_as_float(e0.y) * sup2[(size_t)e0.x * H2F + f];
            a1 += __int_as_float(e1.y) * sup2[(size_t)e1.x * H2F + f];
            a2 += __int_as_float(e2.y) * sup2[(size_t)e2.x * H2F + f];
            a3 += __int_as_float(e3.y) * sup2[(size_t)e3.x * H2F + f];
        }
        for (; j < n; ++j) {
            int2 e0 = eds[j];
            a0 += __int_as_float(e0.y) * sup2[(size_t)e0.x * H2F + f];
        }
    }
    float acc = (a0 + a1) + (a2 + a3);
    acc = fmaxf(acc + b2[f], 0.f);
    zout[(size_t)node * H2F + f] = acc;
    zb[(size_t)node * H2F + f] = f2bf(acc);
}

// ---------- decoder: recon = sigmoid(zb @ zb^T) via bf16 MFMA 32x32x16 ----------
// Gram symmetry: A/B frags of Z rows share lane layouts; C/D layout HW-verified:
// col = lane&31, row = (reg&3) + 8*(reg>>2) + 4*(lane>>5)
__global__ __launch_bounds__(256) void k_decoder(const unsigned short* __restrict__ zb,
                                                 float* __restrict__ recon) {
    int t = threadIdx.x;
    int wave = t >> 6, lane = t & 63;
    int i0 = blockIdx.y * 64 + (wave >> 1) * 32;
    int j0 = blockIdx.x * 64 + (wave & 1) * 32;
    int r = lane & 31, half = lane >> 5;
    int arow = i0 + r, brow = j0 + r;

    short8 zero8 = {0,0,0,0,0,0,0,0};
    short8 a[4], b[4];
    #pragma unroll
    for (int s = 0; s < 4; ++s) {
        a[s] = (arow < N_NODES) ? *(const short8*)(zb + (size_t)arow * H2F + s * 16 + half * 8)
                                : zero8;
        b[s] = (brow < N_NODES) ? *(const short8*)(zb + (size_t)brow * H2F + s * 16 + half * 8)
                                : zero8;
    }

    f32x16 acc;
    #pragma unroll
    for (int i = 0; i < 16; ++i) acc[i] = 0.f;
    #pragma unroll
    for (int s = 0; s < 4; ++s)
        acc = __builtin_amdgcn_mfma_f32_32x32x16_bf16(a[s], b[s], acc, 0, 0, 0);

    #pragma unroll
    for (int rg = 0; rg < 16; ++rg) {
        int row = i0 + (rg & 3) + 8 * (rg >> 2) + 4 * half;
        int col = j0 + r;
        if (row < N_NODES && col < N_NODES) {
            float sv = acc[rg];
            recon[(size_t)row * N_NODES + col] = 1.0f / (1.0f + __expf(-sv));
        }
    }
}

extern "C" void kernel_launch(void* const* d_in, const int* in_sizes, int n_in,
                              void* d_out, int out_size, void* d_ws, size_t ws_size,
                              hipStream_t stream) {
    int ix = -1, iW1 = -1, ib1 = -1, iW2 = -1, ib2 = -1, ic0 = -1, ic1 = -1, ic2 = -1;
    for (int i = 0; i < n_in; ++i) {
        int s = in_sizes[i];
        if      (s == N_NODES * IN_F) ix = i;
        else if (s == IN_F * H1F)     iW1 = i;
        else if (s == H1F)            ib1 = i;
        else if (s == H1F * H2F)      iW2 = i;
        else if (s == H2F)            ib2 = i;
        else if (s == N_EDGES) { if (ic0 < 0) ic0 = i; else if (ic1 < 0) ic1 = i; else ic2 = i; }
    }
    if (ix < 0 || iW1 < 0 || ib1 < 0 || iW2 < 0 || ib2 < 0 || ic0 < 0 || ic1 < 0 || ic2 < 0) {
        ix = 0; iW1 = 1; ib1 = 2; iW2 = 3; ib2 = 4; ic0 = 5; ic1 = 6; ic2 = 7;
    }
    const float* x  = (const float*)d_in[ix];
    const float* W1 = (const float*)d_in[iW1];
    const float* b1 = (const float*)d_in[ib1];
    const float* W2 = (const float*)d_in[iW2];
    const float* b2 = (const float*)d_in[ib2];
    const int*   c0  = (const int*)d_in[ic0];
    const int*   c1  = (const int*)d_in[ic1];
    const int*   c2  = (const int*)d_in[ic2];
    const float* c0f = (const float*)d_in[ic0];
    const float* c2f = (const float*)d_in[ic2];

    float* zout  = (float*)d_out;                        // z: 640000 fp32
    float* recon = zout + (size_t)N_NODES * H2F;         // recon: 1e8 fp32 (400 MB)

    unsigned short* zb = (unsigned short*)d_ws;          // 1.28 MB (decoder input)

    // Scratch inside fp32 recon region (dead before k_decoder overwrites it).
    char* scratch = (char*)recon;
    size_t o = 0;
    auto alloc = [&](size_t bytes) { size_t p = o; o += (bytes + 255) & ~(size_t)255; return p; };
    int*            deg    = (int*)           (scratch + alloc((size_t)N_NODES * 4));
    int*            off    = (int*)           (scratch + alloc((size_t)(N_NODES + 1) * 4));
    int*            cursor = (int*)           (scratch + alloc((size_t)N_NODES * 4));
    int2*           ep     = (int2*)          (scratch + alloc((size_t)N_EDGES * 8));
    unsigned short* sup1b  = (unsigned short*)(scratch + alloc((size_t)N_NODES * H1F * 2));
    float*          h1     = (float*)         (scratch + alloc((size_t)N_NODES * H1F * 4));
    float*          sup2   = (float*)         (scratch + alloc((size_t)N_NODES * H2F * 4));

    hipMemsetAsync(deg, 0, (size_t)N_NODES * 4, stream);
    k_hist  <<<(N_EDGES + 255) / 256, 256, 0, stream>>>(c0, c2, deg);
    k_scan  <<<1, 1024, 0, stream>>>(deg, off, cursor);
    k_bucket<<<(N_EDGES + 255) / 256, 256, 0, stream>>>(c0, c1, c2, c0f, c2f, cursor, ep);

    k_gemm1<<<N_NODES / 8, 256, 0, stream>>>(x, W1, sup1b);
    k_agg1 <<<N_NODES, 256, 0, stream>>>(sup1b, off, ep, b1, h1);

    k_gemm2<<<N_NODES / 4, 64, 0, stream>>>(h1, W2, sup2);
    k_agg2 <<<N_NODES, 64, 0, stream>>>(sup2, off, ep, b2, zout, zb);

    dim3 dgrid((N_NODES + 63) / 64, (N_NODES + 63) / 64);
    k_decoder<<<dgrid, 256, 0, stream>>>(zb, recon);
}